// Round 2
// baseline (44320.544 us; speedup 1.0000x reference)
//
#include <hip/hip_runtime.h>
#include <math.h>

#define B 4
#define SEQ 33
#define MAXLEN 32
#define D 640
#define NH 8
#define DH 80
#define DHP 128      // padded KV row (512B) so fetch-granule pairs never cross positions
#define NL 6
#define FF 2560
#define V 30000
#define INITLEN 8
#define NBLK 1024
#define NT 256
#define EOS_TOK 2
#define NPOS_P 9
#define NR_P 36
#define LM_NB 938   // ceil(30000/32)

// decode stage block ranges (disjoint -> per-XCD L2 weight residency)
#define S1N 120
#define S2B 120
#define S2N 64
#define S3B 184
#define S3N 160
#define S4B 344
#define S4N 80

// striped stage flags
#define NFLAGS 1024
#define NSLOT 32
#define SLOT_U 16

typedef float f4 __attribute__((ext_vector_type(4)));

struct Par {
  const int* iw;
  const float* emb;
  const float *Wq, *bq, *Wk, *bk, *Wv, *bv, *Wo, *bo;
  const float *ln1s, *ln1b, *W1, *b1, *W2, *b2, *ln2s, *ln2b, *lmW, *lmb;
  int* out;
};

// ---------------- persistent device scratch ----------------------------------
__device__ __align__(256) float g_Kc[(size_t)NL * B * NH * SEQ * DHP];
__device__ __align__(256) float g_Vc[(size_t)NL * B * NH * SEQ * DHP];
__device__ __align__(256) float g_x[B * D];          // write-once (RLp)
// versioned decode buffers (write-once per (t,l) -> cached reads are safe)
__device__ __align__(256) float g_qv[(size_t)SEQ * NL * D * B];            // [t][l][col][b]
__device__ __align__(256) float g_opartv[(size_t)SEQ * NL * NH * D * B];   // [t][l][h][col][b]
__device__ __align__(256) float g_f1v[(size_t)SEQ * NL * FF * B];          // [t][l][f][b] (relu'd)
__device__ __align__(256) float g_f2v[(size_t)SEQ * NL * B * D];           // [t][l][b][col]
__device__ __align__(256) float g_h1v[(size_t)SEQ * NL * B * D];           // [t][l][b][col]
__device__ __align__(256) int   g_tokv[SEQ * 64];                          // [t][pad]
__device__ __align__(256) int   g_stopv[SEQ * 64];
// prefill buffers (sc1 both sides, unchanged)
__device__ float g_xp[NR_P * D];
__device__ float g_h1p[NR_P * D];
__device__ float g_qkvpP[(size_t)8 * 1920 * NR_P];
__device__ float g_qP[(size_t)NH * NR_P * DH];
__device__ float g_opartP[(size_t)NH * D * NR_P];
__device__ float g_f1pP[(size_t)8 * FF * NR_P];
__device__ float g_f2pP[(size_t)32 * D * NR_P];
// control
__device__ unsigned long long g_keys[(size_t)NBLK * B];
__device__ int g_tokens[B * SEQ];
__device__ unsigned g_flags[(size_t)NFLAGS * NSLOT * SLOT_U];
__device__ unsigned g_arrive = 0;
__device__ unsigned g_gen = 0;

#define KCIDX(l,b,h,pos,j) (((((size_t)(l)*B+(b))*NH+(h))*SEQ+(pos))*DHP+(j))
#define QVIDX(t,l,col)     ((((size_t)(t)*NL+(l))*D + (col))*B)
#define OPIDX(t,l,h,col)   (((((size_t)(t)*NL+(l))*NH+(h))*D + (col))*B)
#define F1IDX(t,l,f)       ((((size_t)(t)*NL+(l))*FF + (f))*B)
#define HVIDX(t,l,b,col)   ((((size_t)(t)*NL+(l))*B+(b))*D + (col))

// ---------------- coherent scalar access (sc1) -------------------------------
__device__ __forceinline__ float ldc(const float* p) {
  return __hip_atomic_load(p, __ATOMIC_RELAXED, __HIP_MEMORY_SCOPE_AGENT);
}
__device__ __forceinline__ void stc(float* p, float v) {
  __hip_atomic_store(p, v, __ATOMIC_RELAXED, __HIP_MEMORY_SCOPE_AGENT);
}
__device__ __forceinline__ int ldci(const int* p) {
  return __hip_atomic_load(p, __ATOMIC_RELAXED, __HIP_MEMORY_SCOPE_AGENT);
}
__device__ __forceinline__ void stci(int* p, int v) {
  __hip_atomic_store(p, v, __ATOMIC_RELAXED, __HIP_MEMORY_SCOPE_AGENT);
}
__device__ __forceinline__ unsigned long long ldcu64(const unsigned long long* p) {
  return __hip_atomic_load(p, __ATOMIC_RELAXED, __HIP_MEMORY_SCOPE_AGENT);
}
__device__ __forceinline__ void stcu64(unsigned long long* p, unsigned long long v) {
  __hip_atomic_store(p, v, __ATOMIC_RELAXED, __HIP_MEMORY_SCOPE_AGENT);
}
// coherent 16B store: write-through to the device coherence point (MALL)
__device__ __forceinline__ void st4c(float* p, f4 v) {
  asm volatile("global_store_dwordx4 %0, %1, off sc1" :: "v"(p), "v"(v) : "memory");
}

// ---------------- init-time full grid barrier --------------------------------
__device__ __forceinline__ void gsync_full() {
  __syncthreads();
  if (threadIdx.x == 0) {
    __threadfence();
    unsigned g = __hip_atomic_load(&g_gen, __ATOMIC_SEQ_CST, __HIP_MEMORY_SCOPE_AGENT);
    unsigned old = __hip_atomic_fetch_add(&g_arrive, 1u, __ATOMIC_SEQ_CST, __HIP_MEMORY_SCOPE_AGENT);
    if (old == NBLK - 1u) {
      __hip_atomic_store(&g_arrive, 0u, __ATOMIC_SEQ_CST, __HIP_MEMORY_SCOPE_AGENT);
      __hip_atomic_fetch_add(&g_gen, 1u, __ATOMIC_SEQ_CST, __HIP_MEMORY_SCOPE_AGENT);
    } else {
      while (__hip_atomic_load(&g_gen, __ATOMIC_RELAXED, __HIP_MEMORY_SCOPE_AGENT) == g)
        __builtin_amdgcn_s_sleep(2);
    }
    __threadfence();
  }
  __syncthreads();
}

// ---------------- fence-free striped stage sync ------------------------------
__device__ __forceinline__ void stage_done(int idx) {
  asm volatile("s_waitcnt vmcnt(0)" ::: "memory");  // every wave drains its stores
  __syncthreads();
  if (threadIdx.x == 0) {
    __hip_atomic_fetch_add(
        &g_flags[((size_t)idx * NSLOT + (blockIdx.x & (NSLOT - 1))) * SLOT_U],
        1u, __ATOMIC_RELAXED, __HIP_MEMORY_SCOPE_AGENT);
  }
}

__device__ __forceinline__ void stage_wait(int idx, unsigned cnt) {
  if (threadIdx.x < 64) {
    const unsigned* base = &g_flags[(size_t)idx * NSLOT * SLOT_U];
    int spins = 0;
    for (;;) {
      unsigned v = 0u;
      if (threadIdx.x < NSLOT)
        v = __hip_atomic_load(base + (size_t)threadIdx.x * SLOT_U,
                              __ATOMIC_RELAXED, __HIP_MEMORY_SCOPE_AGENT);
      #pragma unroll
      for (int o = 16; o > 0; o >>= 1) v += __shfl_down(v, o, 64);
      v = __shfl(v, 0, 64);
      if (v >= cnt) break;
      if (spins < 32)       __builtin_amdgcn_s_sleep(2);
      else if (spins < 512) __builtin_amdgcn_s_sleep(8);
      else                  __builtin_amdgcn_s_sleep(32);
      ++spins;
    }
  }
  __syncthreads();
  asm volatile("" ::: "memory");
}

// ---------------- LN helpers -------------------------------------------------
__device__ __forceinline__ float bred_sum(float v, float* s_red) {
  #pragma unroll
  for (int o = 32; o > 0; o >>= 1) v += __shfl_down(v, o, 64);
  __syncthreads();
  if ((threadIdx.x & 63) == 0) s_red[threadIdx.x >> 6] = v;
  __syncthreads();
  return s_red[0] + s_red[1] + s_red[2] + s_red[3];
}

__device__ void ln_inplace(float* row, const float* gam, const float* bet, float* s_red) {
  float ps = 0.f;
  for (int d = threadIdx.x; d < D; d += NT) ps += row[d];
  const float m = bred_sum(ps, s_red) * (1.0f / 640.0f);
  float pv = 0.f;
  for (int d = threadIdx.x; d < D; d += NT) { float t = row[d] - m; pv += t * t; }
  const float var = bred_sum(pv, s_red) * (1.0f / 640.0f);
  const float rstd = 1.0f / sqrtf(var + 1e-6f);
  for (int d = threadIdx.x; d < D; d += NT)
    row[d] = (row[d] - m) * rstd * gam[d] + bet[d];
  __syncthreads();
}

// LN over s_row[b][640], wave w handles row b=w. Ends with syncthreads.
__device__ void ln_rows(float* s_row, const float* gam, const float* bet, float* s_red) {
  const int tid = threadIdx.x;
  const int w = tid >> 6, lane = tid & 63;
  float ps = 0.f;
  for (int i = lane; i < D; i += 64) ps += s_row[w * 640 + i];
  #pragma unroll
  for (int o = 32; o > 0; o >>= 1) ps += __shfl_down(ps, o, 64);
  if (lane == 0) s_red[w] = ps * (1.0f / 640.0f);
  __syncthreads();
  const float m = s_red[w];
  float pv = 0.f;
  for (int i = lane; i < D; i += 64) { float d = s_row[w * 640 + i] - m; pv += d * d; }
  #pragma unroll
  for (int o = 32; o > 0; o >>= 1) pv += __shfl_down(pv, o, 64);
  if (lane == 0) s_red[4 + w] = pv * (1.0f / 640.0f);
  __syncthreads();
  const float rstd = 1.0f / sqrtf(s_red[4 + w] + 1e-6f);
  for (int i = lane; i < D; i += 64)
    s_row[w * 640 + i] = (s_row[w * 640 + i] - m) * rstd * gam[i] + bet[i];
  __syncthreads();
}

// build s_x[b][640] = LN2_{lsrc}(h1v + f2v + b2) (cached reads). Ends synced.
__device__ void build_x2(const Par& p, int t, int lsrc, float* s_x, float* s_red) {
  const int tid = threadIdx.x;
  for (int task = tid; task < 640; task += NT) {
    const int b = task / 160, c4 = (task % 160) * 4;
    f4 h = *(const f4*)&g_h1v[HVIDX(t, lsrc, b, c4)];
    f4 f = *(const f4*)&g_f2v[HVIDX(t, lsrc, b, c4)];
    const float* b2 = p.b2 + (size_t)lsrc * D + c4;
    f4 v;
    v.x = h.x + f.x + b2[0]; v.y = h.y + f.y + b2[1];
    v.z = h.z + f.z + b2[2]; v.w = h.w + f.w + b2[3];
    *(f4*)&s_x[b * 640 + c4] = v;
  }
  __syncthreads();
  ln_rows(s_x, p.ln2s + (size_t)lsrc * D, p.ln2b + (size_t)lsrc * D, s_red);
}

// build s_x[b][640] = emb[tok_b]. Ends synced.
__device__ void build_x_emb(const Par& p, int t, float* s_x) {
  const int tid = threadIdx.x;
  for (int task = tid; task < 640; task += NT) {
    const int b = task / 160, c4 = (task % 160) * 4;
    const int tok = g_tokv[t * 64 + b];
    *(f4*)&s_x[b * 640 + c4] = *(const f4*)&p.emb[(size_t)tok * D + c4];
  }
  __syncthreads();
}

// =================== DECODE STAGES (versioned, cached) =======================

// S1 QKV: blocks [0,120). m=bid/40 (q/k/v), cols (bid%40)*16..+16, full depth.
__device__ void st_QKV(const Par& p, int l, int t, float* s_x, float* s_a, float* s_b, float* s_red) {
  const int bid = blockIdx.x, tid = threadIdx.x;
  const int m = bid / 40, cm0 = (bid % 40) * 16;
  if (l == 0) build_x_emb(p, t, s_x);
  else        build_x2(p, t, l - 1, s_x, s_red);
  const int c = tid & 15, b = (tid >> 4) & 3, qd = tid >> 6;
  const float* Wm = (m == 0 ? p.Wq : m == 1 ? p.Wk : p.Wv) + (size_t)l * D * D + cm0 + c;
  float acc = 0.f;
  const float* xrow = s_x + b * 640;
  for (int dd = qd * 160; dd < qd * 160 + 160; ++dd)
    acc += xrow[dd] * Wm[(size_t)dd * D];
  s_a[tid] = acc;
  __syncthreads();
  if (tid < 64) {
    const int cc = tid & 15, bb = tid >> 4;
    float v = s_a[tid] + s_a[tid + 64] + s_a[tid + 128] + s_a[tid + 192];
    v += (m == 0 ? p.bq : m == 1 ? p.bk : p.bv)[(size_t)l * D + cm0 + cc];
    s_b[cc * 4 + bb] = v;
  }
  __syncthreads();
  if (m == 0) {
    if (tid < 16) st4c(&g_qv[QVIDX(t, l, cm0 + tid)], *(f4*)&s_b[tid * 4]);
  } else {
    const int h = cm0 / 80, j0 = cm0 % 80;
    float* cache = (m == 1) ? g_Kc : g_Vc;
    if (tid < 16) {
      const int bb = tid >> 2, cq = (tid & 3) * 4;
      f4 v;
      v.x = s_b[(cq + 0) * 4 + bb]; v.y = s_b[(cq + 1) * 4 + bb];
      v.z = s_b[(cq + 2) * 4 + bb]; v.w = s_b[(cq + 3) * 4 + bb];
      st4c(&cache[KCIDX(l, bb, h, t, j0 + cq)], v);
    }
  }
}

// S2 ATTN+Wo: blocks [120,184): h=(idx)>>3, c=idx&7.
__device__ void st_AT(const Par& p, int l, int t,
                      float* s_q, float* s_o, float* s_sc, float* s_wo) {
  const int idx = blockIdx.x - S2B, h = idx >> 3, c = idx & 7, tid = threadIdx.x;
  const f4* q4 = (const f4*)&g_qv[QVIDX(t, l, h * 80)];
  for (int j = tid; j < 80; j += NT) {
    f4 q = q4[j];
    s_q[0 * 80 + j] = q.x; s_q[1 * 80 + j] = q.y;
    s_q[2 * 80 + j] = q.z; s_q[3 * 80 + j] = q.w;
  }
  __syncthreads();
  const int nk = t + 1;
  for (int task = tid; task < 4 * nk; task += NT) {
    const int b = task / nk, kp = task % nk;
    const f4* kk = (const f4*)&g_Kc[KCIDX(l, b, h, kp, 0)];
    const float* qq = s_q + b * 80;
    float sd = 0.f;
    #pragma unroll
    for (int j4 = 0; j4 < 20; ++j4) {
      f4 k4 = kk[j4];
      sd += qq[j4 * 4 + 0] * k4.x + qq[j4 * 4 + 1] * k4.y +
            qq[j4 * 4 + 2] * k4.z + qq[j4 * 4 + 3] * k4.w;
    }
    s_sc[b * 33 + kp] = sd / 8.94427190999915878564f;
  }
  __syncthreads();
  if (tid < 4) {
    const int b = tid;
    float m = -1e30f;
    for (int k = 0; k < nk; ++k) m = fmaxf(m, s_sc[b * 33 + k]);
    float sum = 0.f;
    for (int k = 0; k < nk; ++k) { float e = expf(s_sc[b * 33 + k] - m); s_sc[b * 33 + k] = e; sum += e; }
    s_sc[132 + b] = 1.0f / sum;
  }
  __syncthreads();
  for (int task = tid; task < 320; task += NT) {
    const int b = task / 80, j = task % 80;
    float acc = 0.f;
    for (int kp = 0; kp < nk; ++kp)
      acc += s_sc[b * 33 + kp] * g_Vc[KCIDX(l, b, h, kp, j)];
    s_o[b * 80 + j] = acc * s_sc[132 + b];
  }
  __syncthreads();
  if (tid < 240) {
    const int j = tid % 80, sub = tid / 80;
    const int col = c * 80 + j;
    const int d0 = sub * 27, d1 = (sub == 2) ? 80 : d0 + 27;
    const float* Wo = p.Wo + (size_t)l * D * D + col;
    float a0 = 0, a1 = 0, a2 = 0, a3 = 0;
    for (int dd = d0; dd < d1; ++dd) {
      const float w = Wo[(size_t)(h * 80 + dd) * D];
      a0 += s_o[0 * 80 + dd] * w; a1 += s_o[1 * 80 + dd] * w;
      a2 += s_o[2 * 80 + dd] * w; a3 += s_o[3 * 80 + dd] * w;
    }
    float* tp = s_wo + (j * 3 + sub) * 4;
    tp[0] = a0; tp[1] = a1; tp[2] = a2; tp[3] = a3;
  }
  __syncthreads();
  if (tid < 80) {
    const int j = tid, col = c * 80 + j;
    f4 v;
    v.x = s_wo[(j*3+0)*4+0] + s_wo[(j*3+1)*4+0] + s_wo[(j*3+2)*4+0];
    v.y = s_wo[(j*3+0)*4+1] + s_wo[(j*3+1)*4+1] + s_wo[(j*3+2)*4+1];
    v.z = s_wo[(j*3+0)*4+2] + s_wo[(j*3+1)*4+2] + s_wo[(j*3+2)*4+2];
    v.w = s_wo[(j*3+0)*4+3] + s_wo[(j*3+1)*4+3] + s_wo[(j*3+2)*4+3];
    st4c(&g_opartv[OPIDX(t, l, h, col)], v);
  }
}

// S3 F1 (+LN1 fused, writes h1): blocks [184,344): cols idx*16..+16.
__device__ void st_FF1(const Par& p, int l, int t, float* s_x, float* s_a, float* s_b, float* s_red) {
  const int idx = blockIdx.x - S3B, tid = threadIdx.x;
  if (l == 0) build_x_emb(p, t, s_x);
  else        build_x2(p, t, l - 1, s_x, s_red);
  for (int col = tid; col < 640; col += NT) {
    f4 o; o.x = 0; o.y = 0; o.z = 0; o.w = 0;
    #pragma unroll
    for (int h = 0; h < 8; ++h) {
      f4 v = *(const f4*)&g_opartv[OPIDX(t, l, h, col)];
      o.x += v.x; o.y += v.y; o.z += v.z; o.w += v.w;
    }
    const float bo = p.bo[(size_t)l * D + col];
    s_x[0 * 640 + col] += o.x + bo;
    s_x[1 * 640 + col] += o.y + bo;
    s_x[2 * 640 + col] += o.z + bo;
    s_x[3 * 640 + col] += o.w + bo;
  }
  __syncthreads();
  ln_rows(s_x, p.ln1s + (size_t)l * D, p.ln1b + (size_t)l * D, s_red);
  if (idx < 4) {
    const int b = idx;
    for (int c4 = tid; c4 < 160; c4 += NT)
      st4c(&g_h1v[HVIDX(t, l, b, c4 * 4)], *(f4*)&s_x[b * 640 + c4 * 4]);
  }
  const int col0 = idx * 16;
  const int c = tid & 15, b = (tid >> 4) & 3, qd = tid >> 6;
  const float* W = p.W1 + (size_t)l * D * FF + col0 + c;
  float acc = 0.f;
  const float* xrow = s_x + b * 640;
  for (int dd = qd * 160; dd < qd * 160 + 160; ++dd)
    acc += xrow[dd] * W[(size_t)dd * FF];
  s_a[tid] = acc;
  __syncthreads();
  if (tid < 64) {
    const int cc = tid & 15, bb = tid >> 4;
    float v = s_a[tid] + s_a[tid + 64] + s_a[tid + 128] + s_a[tid + 192];
    v += p.b1[(size_t)l * FF + col0 + cc];
    s_b[cc * 4 + bb] = fmaxf(v, 0.f);
  }
  __syncthreads();
  if (tid < 16)
    st4c(&g_f1v[F1IDX(t, l, col0 + tid)], *(f4*)&s_b[tid * 4]);
}

// S4 F2: blocks [344,424): cols idx*8..+8, full depth 2560.
__device__ void st_FF2(const Par& p, int l, int t, float* s_a, float* s_b) {
  const int idx = blockIdx.x - S4B, tid = threadIdx.x;
  const int c0 = idx * 8;
  const int c = tid & 7, b = (tid >> 3) & 3, sg = tid >> 5;
  const float* W = p.W2 + (size_t)l * FF * D + c0 + c;
  const float* f1 = &g_f1v[F1IDX(t, l, 0)];
  float acc = 0.f;
  for (int f = sg * 320; f < sg * 320 + 320; ++f)
    acc += f1[(size_t)f * 4 + b] * W[(size_t)f * D];
  s_a[sg * 32 + b * 8 + c] = acc;
  __syncthreads();
  if (tid < 32) {
    const int bb = tid >> 3, cc = tid & 7;
    float v = 0.f;
    #pragma unroll
    for (int s = 0; s < 8; ++s) v += s_a[s * 32 + bb * 8 + cc];
    s_b[cc * 4 + bb] = v;
  }
  __syncthreads();
  if (tid < 8) {
    const int bb = tid >> 1, half = tid & 1;
    f4 v;
    v.x = s_b[(half * 4 + 0) * 4 + bb]; v.y = s_b[(half * 4 + 1) * 4 + bb];
    v.z = s_b[(half * 4 + 2) * 4 + bb]; v.w = s_b[(half * 4 + 3) * 4 + bb];
    st4c(&g_f2v[HVIDX(t, l, bb, c0 + half * 4)], v);
  }
}

// LM: blocks [0,938): 32 cols each (8 quads), depth 640 split over 32 dgroups.
__device__ void st_LM(const Par& p, int t, int src, float* s_xf, float* s_part,
                      unsigned long long* s_key, float* s_red) {
  const int bid = blockIdx.x, tid = threadIdx.x;
  if (src == 0) {
    for (int i4 = tid; i4 < 640; i4 += NT)
      *(f4*)&s_xf[i4 * 4] = *(const f4*)&g_x[i4 * 4];
    __syncthreads();
  } else {
    build_x2(p, t, NL - 1, s_xf, s_red);
  }
  const int quad = tid & 7, dgrp = tid >> 3;
  const int col0 = bid * 32;
  float acc[4][4];
  #pragma unroll
  for (int i = 0; i < 4; ++i)
    #pragma unroll
    for (int j = 0; j < 4; ++j) acc[i][j] = 0.f;
  if (col0 + quad * 4 < V) {
    for (int i = 0; i < 20; ++i) {
      const int d = dgrp * 20 + i;
      f4 w = *(const f4*)&p.lmW[(size_t)d * V + col0 + quad * 4];
      #pragma unroll
      for (int b = 0; b < 4; ++b) {
        const float xv = s_xf[b * 640 + d];
        acc[0][b] += w.x * xv; acc[1][b] += w.y * xv;
        acc[2][b] += w.z * xv; acc[3][b] += w.w * xv;
      }
    }
  }
  #pragma unroll
  for (int o = 32; o >= 8; o >>= 1)
    #pragma unroll
    for (int i = 0; i < 4; ++i)
      #pragma unroll
      for (int j = 0; j < 4; ++j)
        acc[i][j] += __shfl_down(acc[i][j], o, 64);
  if ((tid & 63) < 8) {
    const int w = tid >> 6;
    float* dst = s_part + (w * 8 + quad) * 16;
    #pragma unroll
    for (int i = 0; i < 4; ++i)
      #pragma unroll
      for (int j = 0; j < 4; ++j) dst[i * 4 + j] = acc[i][j];
  }
  __syncthreads();
  if (tid < 128) {
    const int c32 = tid >> 2, b = tid & 3;
    const int qd = c32 >> 2, cq = c32 & 3;
    const int col = col0 + c32;
    unsigned long long key = 0ull;
    if (col < V) {
      float a = p.lmb[col];
      #pragma unroll
      for (int w = 0; w < 4; ++w) a += s_part[(w * 8 + qd) * 16 + cq * 4 + b];
      unsigned u = __float_as_uint(a);
      u = (u & 0x80000000u) ? ~u : (u | 0x80000000u);
      key = ((unsigned long long)u << 32) | (unsigned)(V - col);
    }
    s_key[c32 * 4 + b] = key;
  }
  __syncthreads();
  if (tid < 4) {
    unsigned long long k0 = 0ull;
    for (int c32 = 0; c32 < 32; ++c32) {
      const unsigned long long k = s_key[c32 * 4 + tid];
      if (k > k0) k0 = k;
    }
    stcu64(&g_keys[(size_t)bid * B + tid], k0);
  }
}

// CTL: block 1023.
__device__ void st_CTL(int t, unsigned long long* s_k64, int* s_ctl) {
  const int tid = threadIdx.x;
  for (int b = 0; b < B; ++b) {
    unsigned long long k = 0ull;
    for (int i = tid; i < LM_NB; i += NT) {
      const unsigned long long kk = ldcu64(&g_keys[(size_t)i * B + b]);
      if (kk > k) k = kk;
    }
    #pragma unroll
    for (int o = 32; o > 0; o >>= 1) {
      const unsigned long long kk = __shfl_down(k, o, 64);
      if (kk > k) k = kk;
    }
    __syncthreads();
    if ((tid & 63) == 0) s_k64[tid >> 6] = k;
    __syncthreads();
    if (tid == 0) {
      unsigned long long k0 = s_k64[0];
      #pragma unroll
      for (int q = 1; q < 4; ++q) if (s_k64[q] > k0) k0 = s_k64[q];
      const int tok = V - (int)(unsigned)(k0 & 0xFFFFFFFFull);
      stci(&g_tokens[b * SEQ + t + 1], tok);
      stci(&g_tokv[(t + 1) * 64 + b], tok);
      s_ctl[b] = tok;
    }
    __syncthreads();
  }
  if (tid == 0) {
    int stop = (t == MAXLEN - 1) ? 1 : 0;
    const bool ae = (s_ctl[0] == EOS_TOK) && (s_ctl[1] == EOS_TOK) &&
                    (s_ctl[2] == EOS_TOK) && (s_ctl[3] == EOS_TOK);
    if (ae) stop = 1;
    stci(&g_stopv[t * 64], stop);
  }
}

// =================== PREFILL STAGES (36 rows, sc1, unchanged) ================

__device__ void st_Qp(const Par& p, int l, float* s_a) {
  const int idx = blockIdx.x, tid = threadIdx.x;
  const int h = idx / 24, rem = idx % 24, s = rem / 3, rg = rem % 3;
  const int r0 = rg * 12, d0 = s * 80;
  for (int i = tid; i < 960; i += NT) {
    const int ri = i / 80, dd = i % 80;
    s_a[i] = ldc(&g_xp[(r0 + ri) * D + d0 + dd]);
  }
  __syncthreads();
  if (tid < 240) {
    const int m = tid / 80, j = tid % 80, col = h * 80 + j;
    const float* W = (m == 0 ? p.Wq : m == 1 ? p.Wk : p.Wv) + (size_t)l * D * D + col;
    float acc[12];
    #pragma unroll
    for (int ri = 0; ri < 12; ++ri) acc[ri] = 0.f;
    for (int dd = 0; dd < 80; ++dd) {
      const float w = W[(size_t)(d0 + dd) * D];
      #pragma unroll
      for (int ri = 0; ri < 12; ++ri) acc[ri] += s_a[ri * 80 + dd] * w;
    }
    float* o = g_qkvpP + ((size_t)s * 1920 + m * 640 + col) * NR_P + r0;
    #pragma unroll
    for (int ri = 0; ri < 12; ++ri) stc(o + ri, acc[ri]);
  }
}

__device__ void st_AWp1(const Par& p, int l) {
  const int idx = blockIdx.x - 192, h = idx >> 2, c = idx & 3, tid = threadIdx.x;
  for (int pp = c; pp < NPOS_P; pp += 4) {
    for (int task = tid; task < 960; task += NT) {
      const int m = task / 320, rem = task % 320, j = rem >> 2, b = rem & 3;
      const int r = pp * 4 + b;
      const int col = m * 640 + h * 80 + j;
      const float* q = g_qkvpP + (size_t)col * NR_P + r;
      float a = 0.f;
      #pragma unroll
      for (int s = 0; s < 8; ++s) a += ldc(q + (size_t)s * 1920 * NR_P);
      a += (m == 0 ? p.bq : m == 1 ? p.bk : p.bv)[(size_t)l * D + h * 80 + j];
      if (m == 0)      stc(&g_qP[((size_t)h * NR_P + r) * DH + j], a);
      else if (m == 1) stc(&g_Kc[KCIDX(l, b, h, pp, j)], a);
      else             stc(&g_Vc[KCIDX(l, b, h, pp, j)], a);
    }
  }
}

__device__ void st_AWp2(const Par& p, int l, float* s_a, float* s_b, float* s_c) {
  const int idx = blockIdx.x - 224, h = idx >> 2, rg = idx & 3, tid = threadIdx.x;
  const int r0 = rg * 9;
  for (int i = tid; i < 720; i += NT) {
    const int ri = i / 80, j = i % 80;
    s_a[i] = ldc(&g_qP[((size_t)h * NR_P + r0 + ri) * DH + j]);
  }
  __syncthreads();
  for (int task = tid; task < 81; task += NT) {
    const int ri = task / 9, kp = task % 9;
    const int r = r0 + ri, pos = r >> 2, b = r & 3;
    if (kp <= pos) {
      const float* kk = g_Kc + KCIDX(l, b, h, kp, 0);
      const float* qq = s_a + ri * 80;
      float sd = 0.f;
      for (int j = 0; j < 80; ++j) sd += qq[j] * ldc(kk + j);
      s_c[ri * 9 + kp] = sd / 8.94427190999915878564f;
    }
  }
  __syncthreads();
  if (tid < 9) {
    const int ri = tid, r = r0 + ri, pos = r >> 2;
    float m = -1e30f;
    for (int k = 0; k <= pos; ++k) m = fmaxf(m, s_c[ri * 9 + k]);
    float sum = 0.f;
    for (int k = 0; k <= pos; ++k) { float e = expf(s_c[ri * 9 + k] - m); s_c[ri * 9 + k] = e; sum += e; }
    s_c[81 + ri] = 1.0f / sum;
  }
  __syncthreads();
  for (int task = tid; task < 720; task += NT) {
    const int ri = task / 80, j = task % 80;
    const int r = r0 + ri, pos = r >> 2, b = r & 3;
    float acc = 0.f;
    for (int kp = 0; kp <= pos; ++kp)
      acc += s_c[ri * 9 + kp] * ldc(&g_Vc[KCIDX(l, b, h, kp, j)]);
    s_b[ri * 80 + j] = acc * s_c[81 + ri];
  }
  __syncthreads();
  if (tid < 160) {
    for (int pass = 0; pass < 4; ++pass) {
      const int col = pass * 160 + tid;
      const float* Wo = p.Wo + (size_t)l * D * D + col;
      float acc[9];
      #pragma unroll
      for (int ri = 0; ri < 9; ++ri) acc[ri] = 0.f;
      for (int dd = 0; dd < 80; ++dd) {
        const float w = Wo[(size_t)(h * 80 + dd) * D];
        #pragma unroll
        for (int ri = 0; ri < 9; ++ri) acc[ri] += s_b[ri * 80 + dd] * w;
      }
      #pragma unroll
      for (int ri = 0; ri < 9; ++ri)
        stc(&g_opartP[((size_t)h * D + col) * NR_P + r0 + ri], acc[ri]);
    }
  }
}

__device__ void st_RFp(const Par& p, int l, float* s_row, float* s_red) {
  const int r = blockIdx.x, tid = threadIdx.x;
  for (int col = tid; col < D; col += NT) {
    float a = ldc(&g_xp[r * D + col]) + p.bo[(size_t)l * D + col];
    #pragma unroll
    for (int h = 0; h < 8; ++h) a += ldc(&g_opartP[((size_t)h * D + col) * NR_P + r]);
    s_row[col] = a;
  }
  __syncthreads();
  ln_inplace(s_row, p.ln1s + (size_t)l * D, p.ln1b + (size_t)l * D, s_red);
  for (int col = tid; col < D; col += NT) stc(&g_h1p[r * D + col], s_row[col]);
}

__device__ void st_F1p(const Par& p, int l, float* s_a) {
  const int idx = blockIdx.x, tid = threadIdx.x;
  const int s = idx / 30, rem = idx % 30, cg = rem / 3, rg = rem % 3;
  const int r0 = rg * 12, d0 = s * 80;
  for (int i = tid; i < 960; i += NT) {
    const int ri = i / 80, dd = i % 80;
    s_a[i] = ldc(&g_h1p[(r0 + ri) * D + d0 + dd]);
  }
  __syncthreads();
  const int col = cg * 256 + tid;
  const float* W = p.W1 + (size_t)l * D * FF + col;
  float acc[12];
  #pragma unroll
  for (int ri = 0; ri < 12; ++ri) acc[ri] = 0.f;
  for (int dd = 0; dd < 80; ++dd) {
    const float w = W[(size_t)(d0 + dd) * FF];
    #pragma unroll
    for (int ri = 0; ri < 12; ++ri) acc[ri] += s_a[ri * 80 + dd] * w;
  }
  float* o = g_f1pP + ((size_t)s * FF + col) * NR_P + r0;
  #pragma unroll
  for (int ri = 0; ri < 12; ++ri) stc(o + ri, acc[ri]);
}

__device__ void st_F2p(const Par& p, int l, float* s_c) {
  const int idx = blockIdx.x - 240, c = idx / 3, rg = idx % 3, tid = threadIdx.x;
  const int r0 = rg * 12;
  for (int task = tid; task < 960; task += NT) {
    const int ri = task / 80, fj = task % 80;
    const int fcol = c * 80 + fj;
    const float* pp = g_f1pP + (size_t)fcol * NR_P + r0 + ri;
    float a = 0.f;
    #pragma unroll
    for (int s = 0; s < 8; ++s) a += ldc(pp + (size_t)s * FF * NR_P);
    a += p.b1[(size_t)l * FF + fcol];
    s_c[ri * 80 + fj] = fmaxf(a, 0.f);
  }
  __syncthreads();
  for (int pass = 0; pass < 3; ++pass) {
    const int col = pass * 256 + tid;
    if (col < D) {
      const float* W = p.W2 + (size_t)l * FF * D + col;
      float acc[12];
      #pragma unroll
      for (int ri = 0; ri < 12; ++ri) acc[ri] = 0.f;
      for (int fj = 0; fj < 80; ++fj) {
        const float w = W[(size_t)(c * 80 + fj) * D];
        #pragma unroll
        for (int ri = 0; ri < 12; ++ri) acc[ri] += s_c[ri * 80 + fj] * w;
      }
      float* o = g_f2pP + ((size_t)c * D + col) * NR_P + r0;
      #pragma unroll
      for (int ri = 0; ri < 12; ++ri) stc(o + ri, acc[ri]);
    }
  }
}

__device__ void st_RQp(const Par& p, int l, float* s_row, float* s_red) {
  const int r = blockIdx.x, tid = threadIdx.x;
  for (int col = tid; col < D; col += NT) {
    float a = ldc(&g_h1p[r * D + col]) + p.b2[(size_t)l * D + col];
    #pragma unroll 8
    for (int c = 0; c < 32; ++c) a += ldc(&g_f2pP[((size_t)c * D + col) * NR_P + r]);
    s_row[col] = a;
  }
  __syncthreads();
  ln_inplace(s_row, p.ln2s + (size_t)l * D, p.ln2b + (size_t)l * D, s_red);
  for (int col = tid; col < D; col += NT) stc(&g_xp[r * D + col], s_row[col]);
}

__device__ void st_RLp(const Par& p, float* s_row, float* s_red) {
  const int b = blockIdx.x, r = 32 + b, tid = threadIdx.x;
  for (int col = tid; col < D; col += NT) {
    float a = ldc(&g_h1p[r * D + col]) + p.b2[(size_t)(NL - 1) * D + col];
    #pragma unroll 8
    for (int c = 0; c < 32; ++c) a += ldc(&g_f2pP[((size_t)c * D + col) * NR_P + r]);
    s_row[col] = a;
  }
  __syncthreads();
  ln_inplace(s_row, p.ln2s + (size_t)(NL - 1) * D, p.ln2b + (size_t)(NL - 1) * D, s_red);
  for (int col = tid; col < D; col += NT) stc(&g_x[b * D + col], s_row[col]);
}

// =================== MAIN ====================================================
__global__ __launch_bounds__(NT, 4) void tfgen(Par p) {
  __shared__ float s_x[2560];
  __shared__ float s_a[1024];
  __shared__ float s_b[768];
  __shared__ float s_c[1024];
  __shared__ float s_wo[960];
  __shared__ float s_red[8];
  __shared__ unsigned long long s_key[128];
  __shared__ int s_ctl[4];

  const int bid = blockIdx.x, tid = threadIdx.x;
  int ep = 0;

  // ---- INIT
  {
    unsigned* f = g_flags + (size_t)bid * NSLOT * SLOT_U;
    for (int i = tid; i < NSLOT * SLOT_U; i += NT) f[i] = 0u;
  }
  if (bid < NR_P) {
    const int pos = bid >> 2, b = bid & 3;
    const int tk = (pos == 0) ? 1 : p.iw[b * INITLEN + pos - 1];
    for (int d = tid; d < D; d += NT) stc(&g_xp[bid * D + d], p.emb[(size_t)tk * D + d]);
  }
  if (bid == NBLK - 1) {
    for (int i = tid; i < B * SEQ; i += NT) {
      const int b = i / SEQ, pos = i % SEQ;
      int tk = 0;
      if (pos == 0) tk = 1;
      else if (pos <= INITLEN) tk = p.iw[b * INITLEN + pos - 1];
      stci(&g_tokens[i], tk);
    }
  }
  gsync_full();

  // ---- PREFILL (unchanged structure)
  int eRQ = -1, eF2last = -1;
  for (int l = 0; l < NL; ++l) {
    const int eQ = ep++;
    if (bid < 192) { if (l > 0) stage_wait(eRQ, 36); st_Qp(p, l, s_a); stage_done(eQ); }
    const int eA1 = ep++;
    if (bid >= 192 && bid < 224) { stage_wait(eQ, 192); st_AWp1(p, l); stage_done(eA1); }
    const int eA2 = ep++;
    if (bid >= 224 && bid < 256) { stage_wait(eA1, 32); st_AWp2(p, l, s_a, s_b, s_c); stage_done(eA2); }
    const int eRF = ep++;
    if (bid < NR_P) { stage_wait(eA2, 32); st_RFp(p, l, s_x, s_red); stage_done(eRF); }
    const int eF1 = ep++;
    if (bid < 240) { stage_wait(eRF, 36); st_F1p(p, l, s_a); stage_done(eF1); }
    const int eF2 = ep++;
    if (bid >= 240 && bid < 336) { stage_wait(eF1, 240); st_F2p(p, l, s_c); stage_done(eF2); }
    eF2last = eF2;
    if (l < NL - 1) {
      eRQ = ep++;
      if (bid < NR_P) { stage_wait(eF2, 96); st_RQp(p, l, s_x, s_red); stage_done(eRQ); }
    }
  }

  // ---- DECODE
  for (int t = INITLEN;; ++t) {
    int eCTL;
    if (t == INITLEN) {
      const int eRL = ep++;
      if (bid < 4) { stage_wait(eF2last, 96); st_RLp(p, s_x, s_red); stage_done(eRL); }
      const int eLM = ep++;
      if (bid < LM_NB) { stage_wait(eRL, 4); st_LM(p, t, 0, s_x, s_a, s_key, s_red); stage_done(eLM); }
      eCTL = ep++;
      if (bid == NBLK - 1) { stage_wait(eLM, LM_NB); st_CTL(t, s_key, s_ctl); stage_done(eCTL); }
    } else {
      int eF2s = -1;
      for (int l = 0; l < NL; ++l) {
        const int eQ = ep++;
        if (bid < S1N) {
          if (l > 0) stage_wait(eF2s, S4N);
          st_QKV(p, l, t, s_x, s_a, s_b, s_red);
          stage_done(eQ);
        }
        const int eA = ep++;
        if (bid >= S2B && bid < S2B + S2N) {
          stage_wait(eQ, S1N);
          st_AT(p, l, t, s_a, s_b, s_c, s_wo);
          stage_done(eA);
        }
        const int eF1s = ep++;
        if (bid >= S3B && bid < S3B + S3N) {
          stage_wait(eA, S2N);
          st_FF1(p, l, t, s_x, s_a, s_b, s_red);
          stage_done(eF1s);
        }
        eF2s = ep++;
        if (bid >= S4B && bid < S4B + S4N) {
          stage_wait(eF1s, S3N);
          st_FF2(p, l, t, s_a, s_b);
          stage_done(eF2s);
        }
      }
      const int eLM = ep++;
      if (bid < LM_NB) { stage_wait(eF2s, S4N); st_LM(p, t, 1, s_x, s_a, s_key, s_red); stage_done(eLM); }
      eCTL = ep++;
      if (bid == NBLK - 1) { stage_wait(eLM, LM_NB); st_CTL(t, s_key, s_ctl); stage_done(eCTL); }
    }
    stage_wait(eCTL, 1);
    const int stop = g_stopv[t * 64];
    if (stop) break;
  }

  if (bid == 0) {
    for (int i = tid; i < B * MAXLEN; i += NT) {
      const int b = i >> 5, j = i & 31;
      p.out[i] = ldci(&g_tokens[b * SEQ + j + 1]);
    }
  }
}

extern "C" void kernel_launch(void* const* d_in, const int* in_sizes, int n_in,
                              void* d_out, int out_size, void* d_ws, size_t ws_size,
                              hipStream_t stream)
{
  (void)in_sizes; (void)n_in; (void)out_size; (void)d_ws; (void)ws_size;
  Par p;
  p.iw   = (const int*)  d_in[0];
  p.emb  = (const float*)d_in[2];
  p.Wq   = (const float*)d_in[3];  p.bq   = (const float*)d_in[4];
  p.Wk   = (const float*)d_in[5];  p.bk   = (const float*)d_in[6];
  p.Wv   = (const float*)d_in[7];  p.bv   = (const float*)d_in[8];
  p.Wo   = (const float*)d_in[9];  p.bo   = (const float*)d_in[10];
  p.ln1s = (const float*)d_in[11]; p.ln1b = (const float*)d_in[12];
  p.W1   = (const float*)d_in[13]; p.b1   = (const float*)d_in[14];
  p.W2   = (const float*)d_in[15]; p.b2   = (const float*)d_in[16];
  p.ln2s = (const float*)d_in[17]; p.ln2b = (const float*)d_in[18];
  p.lmW  = (const float*)d_in[19]; p.lmb  = (const float*)d_in[20];
  p.out  = (int*)d_out;

  void* args[] = { (void*)&p };
  hipError_t err = hipLaunchCooperativeKernel((const void*)tfgen, dim3(NBLK), dim3(NT),
                                              args, 0, stream);
  if (err != hipSuccess) {
    // __launch_bounds__(256,4) guarantees 4 blocks/CU co-residency on 256 CUs.
    hipLaunchKernelGGL(tfgen, dim3(NBLK), dim3(NT), 0, stream, p);
  }
}